// Round 1
// baseline (318.712 us; speedup 1.0000x reference)
//
#include <hip/hip_runtime.h>

#define BATCH 8
#define SLEN  2048
#define DDIM  512
#define NQT   32   // 64-row q-tiles per batch

typedef _Float16 f16;
typedef _Float16 half8  __attribute__((ext_vector_type(8)));
typedef _Float16 half4v __attribute__((ext_vector_type(4)));
typedef float    floatx4 __attribute__((ext_vector_type(4)));

// async global->LDS DMA, 16 B/lane; LDS dest = wave-uniform base + lane*16
__device__ __forceinline__ void gld16(const f16* g, f16* l) {
  __builtin_amdgcn_global_load_lds(
      (const __attribute__((address_space(1))) void*)g,
      (__attribute__((address_space(3))) void*)l, 16, 0, 0);
}

// ---------------- pre-pass: K -> fp16 [B][S][D], V -> fp16 transposed [B][D][S] ----------------
__global__ __launch_bounds__(256) void prep_kernel(
    const float* __restrict__ Kin, const float* __restrict__ Vin,
    f16* __restrict__ Khg, f16* __restrict__ Vtg)
{
  __shared__ f16 vt[64][264];
  const int tid = threadIdx.x;
  const int bid = blockIdx.x;
  if (bid < 2048) {
    const int base = bid * 1024 + tid;
#pragma unroll
    for (int i = 0; i < 4; ++i) {
      const int i4 = base + i * 256;
      float4 v = ((const float4*)Kin)[i4];
      half4v h;
      h.x = (f16)v.x; h.y = (f16)v.y; h.z = (f16)v.z; h.w = (f16)v.w;
      *(half4v*)(Khg + (size_t)i4 * 4) = h;
    }
  } else {
    const int vb  = bid - 2048;
    const int b   = vb >> 6;
    const int rem = vb & 63;
    const int s0  = (rem >> 3) * 256;
    const int d0  = (rem & 7) * 64;
    const float* Vb = Vin + (size_t)b * SLEN * DDIM;
    const int d4 = (tid & 15) * 4;
    const int sb = (tid >> 4) * 4;
#pragma unroll
    for (int i = 0; i < 4; ++i) {
      const int ss = sb + i * 64;
      float fa[4][4];
#pragma unroll
      for (int j = 0; j < 4; ++j) {
        float4 f = *(const float4*)(Vb + (size_t)(s0 + ss + j) * DDIM + d0 + d4);
        fa[j][0] = f.x; fa[j][1] = f.y; fa[j][2] = f.z; fa[j][3] = f.w;
      }
#pragma unroll
      for (int k = 0; k < 4; ++k) {
        half4v hv;
        hv.x = (f16)fa[0][k]; hv.y = (f16)fa[1][k];
        hv.z = (f16)fa[2][k]; hv.w = (f16)fa[3][k];
        *(half4v*)&vt[d4 + k][ss] = hv;
      }
    }
    __syncthreads();
    f16* VtB = Vtg + (size_t)b * DDIM * SLEN;
#pragma unroll
    for (int i = 0; i < 8; ++i) {
      const int c    = tid + i * 256;
      const int rd   = c >> 5;
      const int sseg = c & 31;
      *(int4*)(VtB + (size_t)(d0 + rd) * SLEN + s0 + sseg * 8) = *(const int4*)&vt[rd][sseg * 8];
    }
  }
}

// ---------------- flash attention, split-K: 512 blocks = 8 b * 32 qt * 2 kh ----------------
// Block 256 thr = 4 waves. Wave = (qh = w>>1, dh = w&1): 32 q-rows (qh half of the
// 64-row tile), d-half dh (256 of 512). QK^T computed as PARTIAL sums over the
// wave's d-half; partials exchanged+transposed through a swizzled f32 LDS slab at
// bar#A (replaces the old P_l round-trip; still 2 barriers/iter). Softmax is done
// redundantly by both dh-waves in A-fragment layout (P is lane-local -> PV A-frags
// come straight from registers). Defer-max (THR=8) skips the O rescale unless the
// running max grows by >8; epilogue normalizes by 1/l and stores m+log(l), l=1.
//   top:  DMA V(kt)        drains at bar#A
//   QK_partial(kt) on K    (K(kt) DMA'd in kt-1, drained at bar#B(kt-1))
//   write S partial
//   bar#A
//   DMA K(kt+1)            drains at bar#B
//   read S (both halves), add, softmax, P in regs
//   PV(kt) on V
//   bar#B
__global__ __launch_bounds__(256, 2) void attn_kernel(
    const float* __restrict__ Q, const f16* __restrict__ Khg,
    const f16* __restrict__ Vtg, float* __restrict__ O0,
    f16* __restrict__ O1, float* __restrict__ ML)
{
  __shared__ f16  K_l[32][512];       // 32,768 B [key][d], rows XOR-swizzled (16B granule)
  __shared__ f16  V_l[4][512][8];     // 32,768 B [key_oct][d][key%8]
  __shared__ float S_l[4][32][32];    // 16,384 B [qh*2+dh][q][k], rows XOR-swizzled
  // total 81,920 B -> exactly 2 blocks/CU

  const int tid  = threadIdx.x;
  const int lane = tid & 63;
  const int w    = tid >> 6;
  const int qh   = w >> 1;
  const int dh   = w & 1;
  const int col  = lane & 15;
  const int quad = lane >> 4;
  const int bid  = blockIdx.x;
  const int b    = bid & 7;            // batch == XCD slot
  const int qt   = (bid >> 3) & 31;
  const int kh   = bid >> 8;           // key-half
  const int q0   = qt * 64;
  const int k00  = kh * 1024;

  const f16* KhB = Khg + (size_t)b * SLEN * DDIM;
  const f16* VtB = Vtg + (size_t)b * DDIM * SLEN;

  // Q A-frags: A[m-tile][dc]: rows q0+qh*32+m*16+col, d = dh*256 + dc*32 + quad*8 + j
  half8 qf[2][8];
#pragma unroll
  for (int m = 0; m < 2; ++m) {
    const float* Qr = Q + (size_t)(b * SLEN + q0 + qh * 32 + m * 16 + col) * DDIM
                        + dh * 256 + quad * 8;
#pragma unroll
    for (int dc = 0; dc < 8; ++dc) {
      float4 f0 = *(const float4*)(Qr + dc * 32);
      float4 f1 = *(const float4*)(Qr + dc * 32 + 4);
      half8 hq;
      hq[0] = (f16)f0.x; hq[1] = (f16)f0.y; hq[2] = (f16)f0.z; hq[3] = (f16)f0.w;
      hq[4] = (f16)f1.x; hq[5] = (f16)f1.y; hq[6] = (f16)f1.z; hq[7] = (f16)f1.w;
      qf[m][dc] = hq;
    }
  }

  // loop-invariant LDS addressing
  const int   c7s = (col & 7) << 4;                         // XOR swizzle for this lane's rows
  const char* kp0 = (const char*)&K_l[col][0];
  const char* kp1 = (const char*)&K_l[col + 16][0];
  const int   kbase = dh * 512;                             // byte base of d-half in a K row
  const char* vpB = (const char*)&V_l[quad][dh * 256 + col][0];
  char*       Sw  = (char*)&S_l[qh * 2 + dh][0][0];
  const char* Sr0 = (const char*)&S_l[qh * 2 + 0][0][0];
  const char* Sr1 = (const char*)&S_l[qh * 2 + 1][0][0];
  const int   cq0 = (quad << 5) ^ c7s;                      // swizzled 16B chunk: k=quad*8..+3
  const int   cq1 = ((quad << 5) + 16) ^ c7s;               // k=quad*8+4..+7
  const int   mrb0 = col << 7;                              // S row base, m=0 (q=col)
  const int   mrb1 = (16 + col) << 7;                       // m=1 (q=col+16)
  int wr_row[4], wr_swz[4];
#pragma unroll
  for (int i = 0; i < 4; ++i) {
    const int qr = quad * 4 + i;
    wr_row[i] = qr << 7;
    wr_swz[i] = (qr & 7) << 4;
  }

  const floatx4 fzero = {0.f, 0.f, 0.f, 0.f};
  floatx4 o[2][16];                   // 32 q x 256 d, private
#pragma unroll
  for (int m = 0; m < 2; ++m)
#pragma unroll
    for (int nt = 0; nt < 16; ++nt) o[m][nt] = fzero;
  float m_i[2] = {-3.0e38f, -3.0e38f};
  float l_i[2] = {0.f, 0.f};

  // prologue: DMA K(0) (source pre-swizzled so linear LDS holds swizzled rows), drain
#pragma unroll
  for (int i = 0; i < 8; ++i) {
    const int r = w + i * 4;
    gld16(KhB + (size_t)(k00 + r) * DDIM + (((lane << 4) ^ ((r & 7) << 4)) >> 1), &K_l[r][0]);
  }
  __syncthreads();

#pragma unroll 1
  for (int kt = 0; kt < 32; ++kt) {
    const int kv0 = k00 + kt * 32;
    // ---- DMA V(kt) ----
#pragma unroll
    for (int i = 0; i < 8; ++i)
      gld16(VtB + (size_t)(i * 64 + lane) * SLEN + kv0 + w * 8, &V_l[w][i * 64][0]);

    // ---- QK^T partial: 32 q x 32 keys, depth 256 (this wave's d-half) ----
    floatx4 sa00 = fzero, sa01 = fzero, sa10 = fzero, sa11 = fzero;
    __builtin_amdgcn_s_setprio(1);
#pragma unroll
    for (int dc = 0; dc < 8; ++dc) {
      const int xo = (kbase + dc * 64 + quad * 16) ^ c7s;
      half8 k0 = *(const half8*)(kp0 + xo);
      half8 k1 = *(const half8*)(kp1 + xo);
      sa00 = __builtin_amdgcn_mfma_f32_16x16x32_f16(qf[0][dc], k0, sa00, 0, 0, 0);
      sa10 = __builtin_amdgcn_mfma_f32_16x16x32_f16(qf[1][dc], k0, sa10, 0, 0, 0);
      sa01 = __builtin_amdgcn_mfma_f32_16x16x32_f16(qf[0][dc], k1, sa01, 0, 0, 0);
      sa11 = __builtin_amdgcn_mfma_f32_16x16x32_f16(qf[1][dc], k1, sa11, 0, 0, 0);
    }
    __builtin_amdgcn_s_setprio(0);

    // ---- write S partial (C-layout scatter into swizzled rows) ----
#pragma unroll
    for (int i = 0; i < 4; ++i) {
      *(float*)(Sw + wr_row[i]        + (((col << 2)     ) ^ wr_swz[i])) = sa00[i];
      *(float*)(Sw + wr_row[i]        + (((col << 2) + 64) ^ wr_swz[i])) = sa01[i];
      *(float*)(Sw + wr_row[i] + 2048 + (((col << 2)     ) ^ wr_swz[i])) = sa10[i];
      *(float*)(Sw + wr_row[i] + 2048 + (((col << 2) + 64) ^ wr_swz[i])) = sa11[i];
    }

    __syncthreads();   // bar#A: V(kt) DMA drained; K(kt) reads done; S visible

    // ---- DMA K(kt+1): max drain window to bar#B ----
    if (kt < 31) {
#pragma unroll
      for (int i = 0; i < 8; ++i) {
        const int r = w + i * 4;
        gld16(KhB + (size_t)(k00 + (kt + 1) * 32 + r) * DDIM
                  + (((lane << 4) ^ ((r & 7) << 4)) >> 1), &K_l[r][0]);
      }
    }

    // ---- S exchange: read both d-half partials in A-layout, add ----
    float s0v[8], s1v[8];
    {
      floatx4 a0 = *(const floatx4*)(Sr0 + mrb0 + cq0);
      floatx4 a1 = *(const floatx4*)(Sr0 + mrb0 + cq1);
      floatx4 b0 = *(const floatx4*)(Sr1 + mrb0 + cq0);
      floatx4 b1 = *(const floatx4*)(Sr1 + mrb0 + cq1);
#pragma unroll
      for (int j = 0; j < 4; ++j) { s0v[j] = a0[j] + b0[j]; s0v[j + 4] = a1[j] + b1[j]; }
      floatx4 c0 = *(const floatx4*)(Sr0 + mrb1 + cq0);
      floatx4 c1 = *(const floatx4*)(Sr0 + mrb1 + cq1);
      floatx4 d0 = *(const floatx4*)(Sr1 + mrb1 + cq0);
      floatx4 d1 = *(const floatx4*)(Sr1 + mrb1 + cq1);
#pragma unroll
      for (int j = 0; j < 4; ++j) { s1v[j] = c0[j] + d0[j]; s1v[j + 4] = c1[j] + d1[j]; }
    }

    // ---- online softmax in A-layout (lane owns q=col+m*16, keys quad*8..+8) ----
    // defer-max: only move the running max (and rescale O) when it grows by >8.
    float al0, al1; int up0, up1;
    {
      float mx = fmaxf(fmaxf(fmaxf(s0v[0], s0v[1]), fmaxf(s0v[2], s0v[3])),
                       fmaxf(fmaxf(s0v[4], s0v[5]), fmaxf(s0v[6], s0v[7])));
      mx = fmaxf(mx, __shfl_xor(mx, 16));
      mx = fmaxf(mx, __shfl_xor(mx, 32));
      up0 = mx > m_i[0] + 8.0f;
      const float mn = up0 ? mx : m_i[0];
      al0 = up0 ? __expf(m_i[0] - mn) : 1.0f;
      m_i[0] = mn;
    }
    {
      float mx = fmaxf(fmaxf(fmaxf(s1v[0], s1v[1]), fmaxf(s1v[2], s1v[3])),
                       fmaxf(fmaxf(s1v[4], s1v[5]), fmaxf(s1v[6], s1v[7])));
      mx = fmaxf(mx, __shfl_xor(mx, 16));
      mx = fmaxf(mx, __shfl_xor(mx, 32));
      up1 = mx > m_i[1] + 8.0f;
      const float mn = up1 ? mx : m_i[1];
      al1 = up1 ? __expf(m_i[1] - mn) : 1.0f;
      m_i[1] = mn;
    }

    // ---- P = exp(s - m) (bounded by e^8), pack to f16 A-frags, row-sum for l ----
    half8 ap0, ap1;
    {
      float p[8], ls = 0.f;
#pragma unroll
      for (int j = 0; j < 8; ++j) { p[j] = __expf(s0v[j] - m_i[0]); ap0[j] = (f16)p[j]; }
      ls = ((p[0] + p[1]) + (p[2] + p[3])) + ((p[4] + p[5]) + (p[6] + p[7]));
      ls += __shfl_xor(ls, 16);
      ls += __shfl_xor(ls, 32);
      l_i[0] = l_i[0] * al0 + ls;
    }
    {
      float p[8], ls = 0.f;
#pragma unroll
      for (int j = 0; j < 8; ++j) { p[j] = __expf(s1v[j] - m_i[1]); ap1[j] = (f16)p[j]; }
      ls = ((p[0] + p[1]) + (p[2] + p[3])) + ((p[4] + p[5]) + (p[6] + p[7]));
      ls += __shfl_xor(ls, 16);
      ls += __shfl_xor(ls, 32);
      l_i[1] = l_i[1] * al1 + ls;
    }

    // ---- deferred O rescale (rare): factor for C-layout row quad*4+i via shfl ----
    if (__any(up0 | up1)) {
#pragma unroll
      for (int i = 0; i < 4; ++i) {
        const float r0 = __shfl(al0, quad * 4 + i);
        const float r1 = __shfl(al1, quad * 4 + i);
#pragma unroll
        for (int nt = 0; nt < 16; ++nt) { o[0][nt][i] *= r0; o[1][nt][i] *= r1; }
      }
    }

    // ---- PV: O[32q][256d] += P(32x32) * V(32x256), A-frags from regs ----
    __builtin_amdgcn_s_setprio(1);
#pragma unroll
    for (int nt = 0; nt < 16; ++nt) {
      half8 vf = *(const half8*)(vpB + nt * 256);
      o[0][nt] = __builtin_amdgcn_mfma_f32_16x16x32_f16(ap0, vf, o[0][nt], 0, 0, 0);
      o[1][nt] = __builtin_amdgcn_mfma_f32_16x16x32_f16(ap1, vf, o[1][nt], 0, 0, 0);
    }
    __builtin_amdgcn_s_setprio(0);

    __syncthreads();   // bar#B: V(kt) reads + S reads done; K(kt+1) DMA drained
  }

  // ---- epilogue: normalize by 1/l, store (m + log l, 1) so merge stays exact ----
  if (dh == 0 && quad == 0) {
#pragma unroll
    for (int m = 0; m < 2; ++m) {
      const int mlb = (((kh << 3) + b) * NQT + qt) * 128 + (qh * 32 + m * 16 + col) * 2;
      ML[mlb]     = m_i[m] + __logf(l_i[m]);
      ML[mlb + 1] = 1.0f;
    }
  }
  const float inv0 = 1.0f / l_i[0];
  const float inv1 = 1.0f / l_i[1];
  const size_t obase = (size_t)(b * SLEN + q0 + qh * 32) * DDIM + dh * 256;
#pragma unroll
  for (int i = 0; i < 4; ++i) {
    const float r0 = __shfl(inv0, quad * 4 + i);
    const float r1 = __shfl(inv1, quad * 4 + i);
    const size_t ro0 = obase + (size_t)(quad * 4 + i) * DDIM;
    const size_t ro1 = obase + (size_t)(16 + quad * 4 + i) * DDIM;
    if (kh == 0) {
#pragma unroll
      for (int nt = 0; nt < 16; ++nt) {
        O0[ro0 + nt * 16 + col] = o[0][nt][i] * r0;
        O0[ro1 + nt * 16 + col] = o[1][nt][i] * r1;
      }
    } else {
#pragma unroll
      for (int nt = 0; nt < 16; ++nt) {
        O1[ro0 + nt * 16 + col] = (f16)(o[0][nt][i] * r0);
        O1[ro1 + nt * 16 + col] = (f16)(o[1][nt][i] * r1);
      }
    }
  }
}

// ---------------- merge: out = (w0*o0' + w1*o1') / (w0*l0 + w1*l1) ----------------
__global__ __launch_bounds__(256) void merge_kernel(
    float* __restrict__ O0, const f16* __restrict__ O1, const float* __restrict__ ML)
{
  __shared__ float wr[64][3];
  const int bid = blockIdx.x;        // 256 = b*32 + qt
  const int b = bid >> 5, qt = bid & 31;
  const int tid = threadIdx.x;
  if (tid < 64) {
    const int b0 = ((0 + b) * NQT + qt) * 128 + tid * 2;
    const int b1 = ((8 + b) * NQT + qt) * 128 + tid * 2;
    float m0 = ML[b0], l0 = ML[b0 + 1];
    float m1 = ML[b1], l1 = ML[b1 + 1];
    float mm = fmaxf(m0, m1);
    float w0 = __expf(m0 - mm), w1 = __expf(m1 - mm);
    wr[tid][0] = w0;
    wr[tid][1] = w1;
    wr[tid][2] = 1.0f / (w0 * l0 + w1 * l1);
  }
  __syncthreads();
  float*      Ob  = O0 + ((size_t)b * SLEN + qt * 64) * DDIM;
  const f16*  O1b = O1 + ((size_t)b * SLEN + qt * 64) * DDIM;
#pragma unroll 4
  for (int it = 0; it < 32; ++it) {
    const int e4 = it * 256 + tid;
    const int r  = e4 >> 7;            // 128 float4 per row
    const int d4 = (e4 & 127) * 4;
    float4 o0 = *(float4*)(Ob + (size_t)r * DDIM + d4);
    half4v o1 = *(const half4v*)(O1b + (size_t)r * DDIM + d4);
    const float w0 = wr[r][0], w1 = wr[r][1], rl = wr[r][2];
    float4 res;
    res.x = (o0.x * w0 + (float)o1.x * w1) * rl;
    res.y = (o0.y * w0 + (float)o1.y * w1) * rl;
    res.z = (o0.z * w0 + (float)o1.z * w1) * rl;
    res.w = (o0.w * w0 + (float)o1.w * w1) * rl;
    *(float4*)(Ob + (size_t)r * DDIM + d4) = res;
  }
}

extern "C" void kernel_launch(void* const* d_in, const int* in_sizes, int n_in,
                              void* d_out, int out_size, void* d_ws, size_t ws_size,
                              hipStream_t stream) {
  const float* Qp = (const float*)d_in[0];
  const float* Kp = (const float*)d_in[1];
  const float* Vp = (const float*)d_in[2];
  float* Op = (float*)d_out;

  // ws: Khg fp16 16 MiB | Vtg fp16 16 MiB | O1 fp16 16 MiB | ML fp32 256 KiB
  f16*   Khg = (f16*)d_ws;
  f16*   Vtg = (f16*)((char*)d_ws + (size_t)16777216);
  f16*   O1  = (f16*)((char*)d_ws + (size_t)33554432);
  float* ML  = (float*)((char*)d_ws + (size_t)50331648);

  prep_kernel<<<dim3(2048 + 512), dim3(256), 0, stream>>>(Kp, Vp, Khg, Vtg);
  attn_kernel<<<dim3(512), dim3(256), 0, stream>>>(Qp, Khg, Vtg, Op, O1, ML);
  merge_kernel<<<dim3(256), dim3(256), 0, stream>>>(Op, O1, ML);
}

// Round 3
// 274.513 us; speedup vs baseline: 1.1610x; 1.1610x over previous
//
#include <hip/hip_runtime.h>

#define BATCH 8
#define SLEN  2048
#define DDIM  512
#define NQT   32   // 64-row q-tiles per batch

typedef _Float16 f16;
typedef _Float16 half8  __attribute__((ext_vector_type(8)));
typedef _Float16 half4v __attribute__((ext_vector_type(4)));
typedef float    floatx4 __attribute__((ext_vector_type(4)));
typedef float    floatx16 __attribute__((ext_vector_type(16)));

// async global->LDS DMA, 16 B/lane; LDS dest = wave-uniform base + lane*16
__device__ __forceinline__ void gld16(const f16* g, f16* l) {
  __builtin_amdgcn_global_load_lds(
      (const __attribute__((address_space(1))) void*)g,
      (__attribute__((address_space(3))) void*)l, 16, 0, 0);
}

// pack 2 f32 -> 2 f16 in one b32 (v_cvt_pkrtz_f16_f32); builtin returns __fp16x2
__device__ __forceinline__ int pk2(float a, float b) {
  auto h = __builtin_amdgcn_cvt_pkrtz(a, b);
  union { decltype(h) v; int i; } u;
  u.v = h;
  return u.i;
}

// ---------------- pre-pass: K -> fp16 [B][S][D], V -> fp16 transposed [B][D][S] ----------------
__global__ __launch_bounds__(256) void prep_kernel(
    const float* __restrict__ Kin, const float* __restrict__ Vin,
    f16* __restrict__ Khg, f16* __restrict__ Vtg)
{
  __shared__ f16 vt[64][264];
  const int tid = threadIdx.x;
  const int bid = blockIdx.x;
  if (bid < 2048) {
    const int base = bid * 1024 + tid;
#pragma unroll
    for (int i = 0; i < 4; ++i) {
      const int i4 = base + i * 256;
      float4 v = ((const float4*)Kin)[i4];
      half4v h;
      h.x = (f16)v.x; h.y = (f16)v.y; h.z = (f16)v.z; h.w = (f16)v.w;
      *(half4v*)(Khg + (size_t)i4 * 4) = h;
    }
  } else {
    const int vb  = bid - 2048;
    const int b   = vb >> 6;
    const int rem = vb & 63;
    const int s0  = (rem >> 3) * 256;
    const int d0  = (rem & 7) * 64;
    const float* Vb = Vin + (size_t)b * SLEN * DDIM;
    const int d4 = (tid & 15) * 4;
    const int sb = (tid >> 4) * 4;
#pragma unroll
    for (int i = 0; i < 4; ++i) {
      const int ss = sb + i * 64;
      float fa[4][4];
#pragma unroll
      for (int j = 0; j < 4; ++j) {
        float4 f = *(const float4*)(Vb + (size_t)(s0 + ss + j) * DDIM + d0 + d4);
        fa[j][0] = f.x; fa[j][1] = f.y; fa[j][2] = f.z; fa[j][3] = f.w;
      }
#pragma unroll
      for (int k = 0; k < 4; ++k) {
        half4v hv;
        hv.x = (f16)fa[0][k]; hv.y = (f16)fa[1][k];
        hv.z = (f16)fa[2][k]; hv.w = (f16)fa[3][k];
        *(half4v*)&vt[d4 + k][ss] = hv;
      }
    }
    __syncthreads();
    f16* VtB = Vtg + (size_t)b * DDIM * SLEN;
#pragma unroll
    for (int i = 0; i < 8; ++i) {
      const int c    = tid + i * 256;
      const int rd   = c >> 5;
      const int sseg = c & 31;
      *(int4*)(VtB + (size_t)(d0 + rd) * SLEN + s0 + sseg * 8) = *(const int4*)&vt[rd][sseg * 8];
    }
  }
}

// ---------------- flash attention, split-K: 512 blocks = 8 b * 32 qt * 2 kh ----------------
// Block 256 thr = 4 waves = 2 pairs. Pair wq owns q-rows wq*32..+31. Within a pair,
// wave dh owns depth-half dh: QK^T partial over d in [dh*256, dh*256+256), and the
// PV output d-half dh (128 acc regs). Swapped QK (mfma(A=K, B=Q)) puts S^T in
// C-layout: lane c owns q-row c; its 16 regs are 16 of the 32 keys (partner
// half-wave g^1 has the rest). Partials are exchanged via a tiny lane-contiguous
// LDS slab (4 b128 writes + 4 reads/wave) across the existing bar#A. Softmax is
// lane-local (15 fmax + 1 shfl_xor(32)); P -> f16 PV A-frags fully in-register via
// cvt_pkrtz + v_permlane32_swap_b32 (no LDS P round-trip). Defer-max THR=8: O
// rescale only when the running max grows by >8 (rare). Epilogue normalizes by 1/l
// and stores ML=(m+log l, 1) so the kh-merge stays exact.
// 2-barrier phase-offset DMA skeleton (unchanged from the 148us kernel):
//   top:  DMA V(kt)            drains at bar#A
//   QK_partial(kt) on K        (K(kt) DMA'd in kt-1, drained at bar#B(kt-1))
//   write S partial
//   bar#A
//   DMA K(kt+1)                drains at bar#B
//   read partner S, add, softmax+pack (registers), PV(kt) on V
//   bar#B
__global__ __launch_bounds__(256, 2) void attn_kernel(
    const float* __restrict__ Q, const f16* __restrict__ Khg,
    const f16* __restrict__ Vtg, float* __restrict__ O0,
    f16* __restrict__ O1, float* __restrict__ ML)
{
  __shared__ f16   K_l[32][512];     // 32,768 B [key][d], rows XOR-swizzled (16B granule)
  __shared__ f16   V_l[4][512][8];   // 32,768 B [plane=key/8][d][key%8]
  __shared__ float S_l[4][4][256];   // 16,384 B [wave][quad][lane*4]: lane-contiguous
  // total 81,920 B -> 2 blocks/CU

  const int tid  = threadIdx.x;
  const int lane = tid & 63;
  const int w    = tid >> 6;
  const int wq   = w >> 1;        // pair: q-rows wq*32..+31
  const int dh   = w & 1;         // depth-half (QK) and d-half (PV out)
  const int c    = lane & 31;
  const int g    = lane >> 5;
  const int bid  = blockIdx.x;
  const int b    = bid & 7;            // batch == XCD slot
  const int qt   = (bid >> 3) & 31;
  const int kh   = bid >> 8;           // key-half
  const int q0   = qt * 64;
  const int k00  = kh * 1024;

  const f16* KhB = Khg + (size_t)b * SLEN * DDIM;
  const f16* VtB = Vtg + (size_t)b * DDIM * SLEN;

  // Q B-frags (this wave's depth-half): lane holds Q[q=c][d = dh*256 + s*16 + g*8 + j]
  half8 qf[16];
  {
    const float* Qr = Q + (size_t)(b * SLEN + q0 + wq * 32 + c) * DDIM + dh * 256 + g * 8;
#pragma unroll
    for (int s = 0; s < 16; ++s) {
      float4 f0 = *(const float4*)(Qr + s * 16);
      float4 f1 = *(const float4*)(Qr + s * 16 + 4);
      half8 hq;
      hq[0] = (f16)f0.x; hq[1] = (f16)f0.y; hq[2] = (f16)f0.z; hq[3] = (f16)f0.w;
      hq[4] = (f16)f1.x; hq[5] = (f16)f1.y; hq[6] = (f16)f1.z; hq[7] = (f16)f1.w;
      qf[s] = hq;
    }
  }

  const char* Krow = (const char*)&K_l[c][0];
  const int   swz  = (c & 7) << 4;
  const int   kdh  = dh * 512;        // byte base of this wave's depth-half in a K row

  floatx16 o[8];                       // 32 q x 256 d (this wave's output d-half)
#pragma unroll
  for (int dt = 0; dt < 8; ++dt)
#pragma unroll
    for (int i = 0; i < 16; ++i) o[dt][i] = 0.f;
  float m_i = -3.0e38f;
  float l_i = 0.f;

  // prologue: DMA K(0) (source pre-swizzled so linear LDS holds swizzled rows), drain
#pragma unroll
  for (int i = 0; i < 8; ++i) {
    const int r = w + i * 4;
    gld16(KhB + (size_t)(k00 + r) * DDIM + (((lane << 4) ^ ((r & 7) << 4)) >> 1), &K_l[r][0]);
  }
  __syncthreads();

#pragma unroll 1
  for (int kt = 0; kt < 32; ++kt) {
    const int kv0 = k00 + kt * 32;
    // ---- DMA V(kt): V_l free (PV readers of kt-1 passed bar#B) ----
#pragma unroll
    for (int i = 0; i < 8; ++i)
      gld16(VtB + (size_t)(i * 64 + lane) * SLEN + kv0 + w * 8, &V_l[w][i * 64][0]);

    // ---- QK^T partial: S^T[32 keys][32 q] over this wave's 256 depth ----
    floatx16 sA;
#pragma unroll
    for (int i = 0; i < 16; ++i) sA[i] = 0.f;
    __builtin_amdgcn_s_setprio(1);
#pragma unroll
    for (int s = 0; s < 16; ++s) {
      half8 kf = *(const half8*)(Krow + ((kdh + s * 32 + g * 16) ^ swz));
      sA = __builtin_amdgcn_mfma_f32_32x32x16_f16(kf, qf[s], sA, 0, 0, 0);
    }
    __builtin_amdgcn_s_setprio(0);

    // ---- write S partial (lane-contiguous -> conflict-free) ----
#pragma unroll
    for (int j = 0; j < 4; ++j) {
      floatx4 q;
      q[0] = sA[4 * j]; q[1] = sA[4 * j + 1]; q[2] = sA[4 * j + 2]; q[3] = sA[4 * j + 3];
      *(floatx4*)&S_l[w][j][lane * 4] = q;
    }

    __syncthreads();   // bar#A: K(kt) reads done; V(kt) DMA drained; S partials visible

    // ---- DMA K(kt+1): K_l free since bar#A, drains at bar#B ----
    if (kt < 31) {
#pragma unroll
      for (int i = 0; i < 8; ++i) {
        const int r = w + i * 4;
        gld16(KhB + (size_t)(k00 + (kt + 1) * 32 + r) * DDIM
                  + (((lane << 4) ^ ((r & 7) << 4)) >> 1), &K_l[r][0]);
      }
    }

    // ---- add partner's partial: full S in registers ----
#pragma unroll
    for (int j = 0; j < 4; ++j) {
      floatx4 pq = *(const floatx4*)&S_l[w ^ 1][j][lane * 4];
      sA[4 * j]     += pq[0];
      sA[4 * j + 1] += pq[1];
      sA[4 * j + 2] += pq[2];
      sA[4 * j + 3] += pq[3];
    }

    // ---- online softmax, lane-local (lane owns q-row c; 16 of 32 keys) ----
    float mx = sA[0];
#pragma unroll
    for (int i = 1; i < 16; ++i) mx = fmaxf(mx, sA[i]);
    mx = fmaxf(mx, __shfl_xor(mx, 32));
    const int   up = mx > m_i + 8.0f;          // defer-max THR=8
    const float mn = up ? mx : m_i;
    const float al = up ? __expf(m_i - mn) : 1.0f;
    m_i = mn;
    float p[16], ls = 0.f;
#pragma unroll
    for (int i = 0; i < 16; ++i) { p[i] = __expf(sA[i] - m_i); ls += p[i]; }
    ls += __shfl_xor(ls, 32);
    l_i = l_i * al + ls;

    // ---- P -> f16 PV A-frags in-register: cvt_pkrtz + permlane32_swap ----
    // reg i holds key (i&3) + 8*(i>>2) + 4g; pairs (2j,2j+1) are adjacent keys.
    int pw[8];
#pragma unroll
    for (int j = 0; j < 8; ++j) pw[j] = pk2(p[2 * j], p[2 * j + 1]);
    // After swaps: g=0 lanes hold keys 0..7 (pw[0..3]) / 16..23 (pw[4..7]);
    // g=1 lanes hold keys 8..15 / 24..31 — exact A-frag order for the two K=16 frags.
    asm volatile("v_permlane32_swap_b32 %0, %1" : "+v"(pw[0]), "+v"(pw[2]));
    asm volatile("v_permlane32_swap_b32 %0, %1" : "+v"(pw[1]), "+v"(pw[3]));
    asm volatile("v_permlane32_swap_b32 %0, %1" : "+v"(pw[4]), "+v"(pw[6]));
    asm volatile("v_permlane32_swap_b32 %0, %1" : "+v"(pw[5]), "+v"(pw[7]));
    union { int i[4]; half8 h; } uf0, uf1;
    uf0.i[0] = pw[0]; uf0.i[1] = pw[1]; uf0.i[2] = pw[2]; uf0.i[3] = pw[3];
    uf1.i[0] = pw[4]; uf1.i[1] = pw[5]; uf1.i[2] = pw[6]; uf1.i[3] = pw[7];
    const half8 pf0 = uf0.h, pf1 = uf1.h;

    // ---- deferred O rescale (rare): O rows are (i&3)+8*(i>>2)+4g ----
    if (__any(up)) {
#pragma unroll
      for (int i = 0; i < 16; ++i) {
        const int   ri = (i & 3) + 8 * (i >> 2) + 4 * g;
        const float fr = __shfl(al, ri);
#pragma unroll
        for (int dt = 0; dt < 8; ++dt) o[dt][i] *= fr;
      }
    }

    // ---- PV: O[32q][256d] += P(32x32) * V(32x256); V B-frag plane = 2t+g ----
    __builtin_amdgcn_s_setprio(1);
#pragma unroll
    for (int dt = 0; dt < 8; ++dt) {
      half8 vf0 = *(const half8*)&V_l[0 + g][dh * 256 + dt * 32 + c][0];
      half8 vf1 = *(const half8*)&V_l[2 + g][dh * 256 + dt * 32 + c][0];
      o[dt] = __builtin_amdgcn_mfma_f32_32x32x16_f16(pf0, vf0, o[dt], 0, 0, 0);
      o[dt] = __builtin_amdgcn_mfma_f32_32x32x16_f16(pf1, vf1, o[dt], 0, 0, 0);
    }
    __builtin_amdgcn_s_setprio(0);

    __syncthreads();   // bar#B: V(kt)+S reads done; K(kt+1) DMA drained
  }

  // ---- epilogue: normalize by 1/l, store (m + log l, 1) so merge stays exact ----
  if (dh == 0 && g == 0) {
    const int mlb = (((kh << 3) + b) * NQT + qt) * 128 + (wq * 32 + c) * 2;
    ML[mlb]     = m_i + __logf(l_i);
    ML[mlb + 1] = 1.0f;
  }
  const float inv = 1.0f / l_i;
  const size_t rbase = (size_t)(b * SLEN + q0 + wq * 32);
#pragma unroll
  for (int i = 0; i < 16; ++i) {
    const int   ri = (i & 3) + 8 * (i >> 2) + 4 * g;
    const float fr = __shfl(inv, ri);
    const size_t ro = (rbase + ri) * DDIM + dh * 256 + c;
    if (kh == 0) {
#pragma unroll
      for (int dt = 0; dt < 8; ++dt) O0[ro + dt * 32] = o[dt][i] * fr;
    } else {
#pragma unroll
      for (int dt = 0; dt < 8; ++dt) O1[ro + dt * 32] = (f16)(o[dt][i] * fr);
    }
  }
}

// ---------------- merge: out = (w0*o0' + w1*o1') / (w0*l0 + w1*l1) ----------------
__global__ __launch_bounds__(256) void merge_kernel(
    float* __restrict__ O0, const f16* __restrict__ O1, const float* __restrict__ ML)
{
  __shared__ float wr[64][3];
  const int bid = blockIdx.x;        // 256 = b*32 + qt
  const int b = bid >> 5, qt = bid & 31;
  const int tid = threadIdx.x;
  if (tid < 64) {
    const int b0 = ((0 + b) * NQT + qt) * 128 + tid * 2;
    const int b1 = ((8 + b) * NQT + qt) * 128 + tid * 2;
    float m0 = ML[b0], l0 = ML[b0 + 1];
    float m1 = ML[b1], l1 = ML[b1 + 1];
    float mm = fmaxf(m0, m1);
    float w0 = __expf(m0 - mm), w1 = __expf(m1 - mm);
    wr[tid][0] = w0;
    wr[tid][1] = w1;
    wr[tid][2] = 1.0f / (w0 * l0 + w1 * l1);
  }
  __syncthreads();
  float*      Ob  = O0 + ((size_t)b * SLEN + qt * 64) * DDIM;
  const f16*  O1b = O1 + ((size_t)b * SLEN + qt * 64) * DDIM;
#pragma unroll 4
  for (int it = 0; it < 32; ++it) {
    const int e4 = it * 256 + tid;
    const int r  = e4 >> 7;            // 128 float4 per row
    const int d4 = (e4 & 127) * 4;
    float4 o0 = *(float4*)(Ob + (size_t)r * DDIM + d4);
    half4v o1 = *(const half4v*)(O1b + (size_t)r * DDIM + d4);
    const float w0 = wr[r][0], w1 = wr[r][1], rl = wr[r][2];
    float4 res;
    res.x = (o0.x * w0 + (float)o1.x * w1) * rl;
    res.y = (o0.y * w0 + (float)o1.y * w1) * rl;
    res.z = (o0.z * w0 + (float)o1.z * w1) * rl;
    res.w = (o0.w * w0 + (float)o1.w * w1) * rl;
    *(float4*)(Ob + (size_t)r * DDIM + d4) = res;
  }
}

extern "C" void kernel_launch(void* const* d_in, const int* in_sizes, int n_in,
                              void* d_out, int out_size, void* d_ws, size_t ws_size,
                              hipStream_t stream) {
  const float* Qp = (const float*)d_in[0];
  const float* Kp = (const float*)d_in[1];
  const float* Vp = (const float*)d_in[2];
  float* Op = (float*)d_out;

  // ws: Khg fp16 16 MiB | Vtg fp16 16 MiB | O1 fp16 16 MiB | ML fp32 256 KiB
  f16*   Khg = (f16*)d_ws;
  f16*   Vtg = (f16*)((char*)d_ws + (size_t)16777216);
  f16*   O1  = (f16*)((char*)d_ws + (size_t)33554432);
  float* ML  = (float*)((char*)d_ws + (size_t)50331648);

  prep_kernel<<<dim3(2048 + 512), dim3(256), 0, stream>>>(Kp, Vp, Khg, Vtg);
  attn_kernel<<<dim3(512), dim3(256), 0, stream>>>(Qp, Khg, Vtg, Op, O1, ML);
  merge_kernel<<<dim3(256), dim3(256), 0, stream>>>(Op, O1, ML);
}

// Round 4
// 272.699 us; speedup vs baseline: 1.1687x; 1.0067x over previous
//
#include <hip/hip_runtime.h>

#define BATCH 8
#define SLEN  2048
#define DDIM  512

typedef _Float16 f16;
typedef _Float16 half8  __attribute__((ext_vector_type(8)));
typedef _Float16 half4v __attribute__((ext_vector_type(4)));
typedef float    floatx4 __attribute__((ext_vector_type(4)));
typedef float    floatx16 __attribute__((ext_vector_type(16)));

// async global->LDS DMA, 16 B/lane; LDS dest = wave-uniform base + lane*16
__device__ __forceinline__ void gld16(const f16* g, f16* l) {
  __builtin_amdgcn_global_load_lds(
      (const __attribute__((address_space(1))) void*)g,
      (__attribute__((address_space(3))) void*)l, 16, 0, 0);
}

// pack 2 f32 -> 2 f16 in one b32 (v_cvt_pkrtz_f16_f32); builtin returns __fp16x2
__device__ __forceinline__ int pk2(float a, float b) {
  auto h = __builtin_amdgcn_cvt_pkrtz(a, b);
  union { decltype(h) v; int i; } u;
  u.v = h;
  return u.i;
}

// ---------------- pre-pass: K -> fp16 [B][S][D], V -> fp16 transposed [B][D][S] ----------------
__global__ __launch_bounds__(256) void prep_kernel(
    const float* __restrict__ Kin, const float* __restrict__ Vin,
    f16* __restrict__ Khg, f16* __restrict__ Vtg)
{
  __shared__ f16 vt[64][264];
  const int tid = threadIdx.x;
  const int bid = blockIdx.x;
  if (bid < 2048) {
    const int base = bid * 1024 + tid;
#pragma unroll
    for (int i = 0; i < 4; ++i) {
      const int i4 = base + i * 256;
      float4 v = ((const float4*)Kin)[i4];
      half4v h;
      h.x = (f16)v.x; h.y = (f16)v.y; h.z = (f16)v.z; h.w = (f16)v.w;
      *(half4v*)(Khg + (size_t)i4 * 4) = h;
    }
  } else {
    const int vb  = bid - 2048;
    const int b   = vb >> 6;
    const int rem = vb & 63;
    const int s0  = (rem >> 3) * 256;
    const int d0  = (rem & 7) * 64;
    const float* Vb = Vin + (size_t)b * SLEN * DDIM;
    const int d4 = (tid & 15) * 4;
    const int sb = (tid >> 4) * 4;
#pragma unroll
    for (int i = 0; i < 4; ++i) {
      const int ss = sb + i * 64;
      float fa[4][4];
#pragma unroll
      for (int j = 0; j < 4; ++j) {
        float4 f = *(const float4*)(Vb + (size_t)(s0 + ss + j) * DDIM + d0 + d4);
        fa[j][0] = f.x; fa[j][1] = f.y; fa[j][2] = f.z; fa[j][3] = f.w;
      }
#pragma unroll
      for (int k = 0; k < 4; ++k) {
        half4v hv;
        hv.x = (f16)fa[0][k]; hv.y = (f16)fa[1][k];
        hv.z = (f16)fa[2][k]; hv.w = (f16)fa[3][k];
        *(half4v*)&vt[d4 + k][ss] = hv;
      }
    }
    __syncthreads();
    f16* VtB = Vtg + (size_t)b * DDIM * SLEN;
#pragma unroll
    for (int i = 0; i < 8; ++i) {
      const int c    = tid + i * 256;
      const int rd   = c >> 5;
      const int sseg = c & 31;
      *(int4*)(VtB + (size_t)(d0 + rd) * SLEN + s0 + sseg * 8) = *(const int4*)&vt[rd][sseg * 8];
    }
  }
}

// ---------------- flash attention, split-K: 256 blocks = 8 b * 16 qt * 2 kh ----------------
// ONE 512-thread block per CU (8 waves = 4 pairs), 128 q-rows per block. The two
// previously co-resident 64-row blocks are merged so they SHARE the K/V staging DMA:
// staged bytes per CU-iter halve (128 KB -> 64 KB), aggregate 1 GB -> 512 MB. Theory:
// the r0/r3 plateau (~150 us regardless of inner-loop cost) is L2/LLC->LDS staging
// bandwidth (~6.6 TB/s sustained), so halving staged volume is the lever.
// Per-wave structure identical to the verified round-3 kernel: pair wq owns q-rows
// wq*32..+31; wave dh in the pair owns depth-half dh (QK partial) and output d-half dh
// (128 acc regs). Swapped QK (mfma(A=K,B=Q)) -> S^T in C-layout, partner partials
// exchanged via lane-contiguous LDS slab across bar#A. Softmax lane-local; P -> f16
// A-frags in-register (cvt_pkrtz + permlane32_swap); defer-max THR=8; epilogue
// normalizes by 1/l and stores ML=(m+log l, 1).
// 2-barrier phase-offset DMA skeleton:
//   top:  DMA V(kt)            drains at bar#A
//   QK_partial(kt) on K        (K(kt) DMA'd in kt-1, drained at bar#B(kt-1))
//   write S partial
//   bar#A
//   DMA K(kt+1)                drains at bar#B
//   read partner S, add, softmax+pack (registers), PV(kt) on V
//   bar#B
__global__ __launch_bounds__(512, 2) void attn_kernel(
    const float* __restrict__ Q, const f16* __restrict__ Khg,
    const f16* __restrict__ Vtg, float* __restrict__ O0,
    f16* __restrict__ O1, float* __restrict__ ML)
{
  __shared__ f16   K_l[32][512];     // 32,768 B [key][d], rows XOR-swizzled (16B granule)
  __shared__ f16   V_l[4][512][8];   // 32,768 B [plane=key/8][d][key%8]
  __shared__ float S_l[8][4][256];   // 32,768 B [wave][quad][lane*4]: lane-contiguous
  // total 98,304 B -> 1 block/CU (8 waves)

  const int tid  = threadIdx.x;
  const int lane = tid & 63;
  const int w    = tid >> 6;      // 0..7
  const int wq   = w >> 1;        // pair: q-rows wq*32..+31 (0..3)
  const int dh   = w & 1;         // depth-half (QK) and d-half (PV out)
  const int c    = lane & 31;
  const int g    = lane >> 5;
  const int bid  = blockIdx.x;
  const int b    = bid & 7;            // batch == XCD slot
  const int qt   = (bid >> 3) & 15;
  const int kh   = bid >> 7;           // key-half
  const int q0   = qt * 128;
  const int k00  = kh * 1024;

  const f16* KhB = Khg + (size_t)b * SLEN * DDIM;
  const f16* VtB = Vtg + (size_t)b * DDIM * SLEN;

  // Q B-frags (this wave's depth-half): lane holds Q[q=c][d = dh*256 + s*16 + g*8 + j]
  half8 qf[16];
  {
    const float* Qr = Q + (size_t)(b * SLEN + q0 + wq * 32 + c) * DDIM + dh * 256 + g * 8;
#pragma unroll
    for (int s = 0; s < 16; ++s) {
      float4 f0 = *(const float4*)(Qr + s * 16);
      float4 f1 = *(const float4*)(Qr + s * 16 + 4);
      half8 hq;
      hq[0] = (f16)f0.x; hq[1] = (f16)f0.y; hq[2] = (f16)f0.z; hq[3] = (f16)f0.w;
      hq[4] = (f16)f1.x; hq[5] = (f16)f1.y; hq[6] = (f16)f1.z; hq[7] = (f16)f1.w;
      qf[s] = hq;
    }
  }

  const char* Krow = (const char*)&K_l[c][0];
  const int   swz  = (c & 7) << 4;
  const int   kdh  = dh * 512;        // byte base of this wave's depth-half in a K row
  const int   vplane = w >> 1;        // DMA: this wave fills plane w>>1, d-half w&1

  floatx16 o[8];                       // 32 q x 256 d (this wave's output d-half)
#pragma unroll
  for (int dt = 0; dt < 8; ++dt)
#pragma unroll
    for (int i = 0; i < 16; ++i) o[dt][i] = 0.f;
  float m_i = -3.0e38f;
  float l_i = 0.f;

  // prologue: DMA K(0) (source pre-swizzled so linear LDS holds swizzled rows), drain
  // 8 waves x 4 rows: r = w + i*8 (r&7 == w, wave-uniform swizzle)
#pragma unroll
  for (int i = 0; i < 4; ++i) {
    const int r = w + i * 8;
    gld16(KhB + (size_t)(k00 + r) * DDIM + (((lane << 4) ^ (w << 4)) >> 1), &K_l[r][0]);
  }
  __syncthreads();

#pragma unroll 1
  for (int kt = 0; kt < 32; ++kt) {
    const int kv0 = k00 + kt * 32;
    // ---- DMA V(kt): wave fills plane w>>1, d-range (w&1)*256..+255 ----
#pragma unroll
    for (int i = 0; i < 4; ++i) {
      const int dbase = dh * 256 + i * 64;
      gld16(VtB + (size_t)(dbase + lane) * SLEN + kv0 + vplane * 8, &V_l[vplane][dbase][0]);
    }

    // ---- QK^T partial: S^T[32 keys][32 q] over this wave's 256 depth ----
    floatx16 sA;
#pragma unroll
    for (int i = 0; i < 16; ++i) sA[i] = 0.f;
    __builtin_amdgcn_s_setprio(1);
#pragma unroll
    for (int s = 0; s < 16; ++s) {
      half8 kf = *(const half8*)(Krow + ((kdh + s * 32 + g * 16) ^ swz));
      sA = __builtin_amdgcn_mfma_f32_32x32x16_f16(kf, qf[s], sA, 0, 0, 0);
    }
    __builtin_amdgcn_s_setprio(0);

    // ---- write S partial (lane-contiguous -> conflict-free) ----
#pragma unroll
    for (int j = 0; j < 4; ++j) {
      floatx4 q;
      q[0] = sA[4 * j]; q[1] = sA[4 * j + 1]; q[2] = sA[4 * j + 2]; q[3] = sA[4 * j + 3];
      *(floatx4*)&S_l[w][j][lane * 4] = q;
    }

    __syncthreads();   // bar#A: K(kt) reads done; V(kt) DMA drained; S partials visible

    // ---- DMA K(kt+1): K_l free since bar#A, drains at bar#B ----
    if (kt < 31) {
#pragma unroll
      for (int i = 0; i < 4; ++i) {
        const int r = w + i * 8;
        gld16(KhB + (size_t)(k00 + (kt + 1) * 32 + r) * DDIM
                  + (((lane << 4) ^ (w << 4)) >> 1), &K_l[r][0]);
      }
    }

    // ---- add partner's partial: full S in registers ----
#pragma unroll
    for (int j = 0; j < 4; ++j) {
      floatx4 pq = *(const floatx4*)&S_l[w ^ 1][j][lane * 4];
      sA[4 * j]     += pq[0];
      sA[4 * j + 1] += pq[1];
      sA[4 * j + 2] += pq[2];
      sA[4 * j + 3] += pq[3];
    }

    // ---- online softmax, lane-local (lane owns q-row c; 16 of 32 keys) ----
    float mx = sA[0];
#pragma unroll
    for (int i = 1; i < 16; ++i) mx = fmaxf(mx, sA[i]);
    mx = fmaxf(mx, __shfl_xor(mx, 32));
    const int   up = mx > m_i + 8.0f;          // defer-max THR=8
    const float mn = up ? mx : m_i;
    const float al = up ? __expf(m_i - mn) : 1.0f;
    m_i = mn;
    float p[16], ls = 0.f;
#pragma unroll
    for (int i = 0; i < 16; ++i) { p[i] = __expf(sA[i] - m_i); ls += p[i]; }
    ls += __shfl_xor(ls, 32);
    l_i = l_i * al + ls;

    // ---- P -> f16 PV A-frags in-register: cvt_pkrtz + permlane32_swap ----
    // reg i holds key (i&3) + 8*(i>>2) + 4g; pairs (2j,2j+1) are adjacent keys.
    int pw[8];
#pragma unroll
    for (int j = 0; j < 8; ++j) pw[j] = pk2(p[2 * j], p[2 * j + 1]);
    // After swaps: g=0 lanes hold keys 0..7 (pw[0..3]) / 16..23 (pw[4..7]);
    // g=1 lanes hold keys 8..15 / 24..31 — exact A-frag order for the two K=16 frags.
    asm volatile("v_permlane32_swap_b32 %0, %1" : "+v"(pw[0]), "+v"(pw[2]));
    asm volatile("v_permlane32_swap_b32 %0, %1" : "+v"(pw[1]), "+v"(pw[3]));
    asm volatile("v_permlane32_swap_b32 %0, %1" : "+v"(pw[4]), "+v"(pw[6]));
    asm volatile("v_permlane32_swap_b32 %0, %1" : "+v"(pw[5]), "+v"(pw[7]));
    union { int i[4]; half8 h; } uf0, uf1;
    uf0.i[0] = pw[0]; uf0.i[1] = pw[1]; uf0.i[2] = pw[2]; uf0.i[3] = pw[3];
    uf1.i[0] = pw[4]; uf1.i[1] = pw[5]; uf1.i[2] = pw[6]; uf1.i[3] = pw[7];
    const half8 pf0 = uf0.h, pf1 = uf1.h;

    // ---- deferred O rescale (rare): O rows are (i&3)+8*(i>>2)+4g ----
    if (__any(up)) {
#pragma unroll
      for (int i = 0; i < 16; ++i) {
        const int   ri = (i & 3) + 8 * (i >> 2) + 4 * g;
        const float fr = __shfl(al, ri);
#pragma unroll
        for (int dt = 0; dt < 8; ++dt) o[dt][i] *= fr;
      }
    }

    // ---- PV: O[32q][256d] += P(32x32) * V(32x256); V B-frag plane = 2t+g ----
    __builtin_amdgcn_s_setprio(1);
#pragma unroll
    for (int dt = 0; dt < 8; ++dt) {
      half8 vf0 = *(const half8*)&V_l[0 + g][dh * 256 + dt * 32 + c][0];
      half8 vf1 = *(const half8*)&V_l[2 + g][dh * 256 + dt * 32 + c][0];
      o[dt] = __builtin_amdgcn_mfma_f32_32x32x16_f16(pf0, vf0, o[dt], 0, 0, 0);
      o[dt] = __builtin_amdgcn_mfma_f32_32x32x16_f16(pf1, vf1, o[dt], 0, 0, 0);
    }
    __builtin_amdgcn_s_setprio(0);

    __syncthreads();   // bar#B: V(kt)+S reads done; K(kt+1) DMA drained
  }

  // ---- epilogue: normalize by 1/l, store ML=(m + log l, 1) so merge stays exact ----
  // ML layout: [((kh*8 + b) * SLEN + row) * 2]
  if (dh == 0 && g == 0) {
    const int mlb = (((kh << 3) + b) * SLEN + q0 + wq * 32 + c) * 2;
    ML[mlb]     = m_i + __logf(l_i);
    ML[mlb + 1] = 1.0f;
  }
  const float inv = 1.0f / l_i;
  const size_t rbase = (size_t)(b * SLEN + q0 + wq * 32);
#pragma unroll
  for (int i = 0; i < 16; ++i) {
    const int   ri = (i & 3) + 8 * (i >> 2) + 4 * g;
    const float fr = __shfl(inv, ri);
    const size_t ro = (rbase + ri) * DDIM + dh * 256 + c;
    if (kh == 0) {
#pragma unroll
      for (int dt = 0; dt < 8; ++dt) O0[ro + dt * 32] = o[dt][i] * fr;
    } else {
#pragma unroll
      for (int dt = 0; dt < 8; ++dt) O1[ro + dt * 32] = (f16)(o[dt][i] * fr);
    }
  }
}

// ---------------- merge: out = (w0*o0' + w1*o1') / (w0*l0 + w1*l1) ----------------
__global__ __launch_bounds__(256) void merge_kernel(
    float* __restrict__ O0, const f16* __restrict__ O1, const float* __restrict__ ML)
{
  __shared__ float wr[64][3];
  const int bid = blockIdx.x;        // 256 = b*32 + t64 (64-row tile)
  const int b = bid >> 5, t64 = bid & 31;
  const int tid = threadIdx.x;
  if (tid < 64) {
    const int row = t64 * 64 + tid;
    const int b0 = (((0 + b) * SLEN) + row) * 2;
    const int b1 = (((8 + b) * SLEN) + row) * 2;
    float m0 = ML[b0], l0 = ML[b0 + 1];
    float m1 = ML[b1], l1 = ML[b1 + 1];
    float mm = fmaxf(m0, m1);
    float w0 = __expf(m0 - mm), w1 = __expf(m1 - mm);
    wr[tid][0] = w0;
    wr[tid][1] = w1;
    wr[tid][2] = 1.0f / (w0 * l0 + w1 * l1);
  }
  __syncthreads();
  float*      Ob  = O0 + ((size_t)b * SLEN + t64 * 64) * DDIM;
  const f16*  O1b = O1 + ((size_t)b * SLEN + t64 * 64) * DDIM;
#pragma unroll 4
  for (int it = 0; it < 32; ++it) {
    const int e4 = it * 256 + tid;
    const int r  = e4 >> 7;            // 128 float4 per row
    const int d4 = (e4 & 127) * 4;
    float4 o0 = *(float4*)(Ob + (size_t)r * DDIM + d4);
    half4v o1 = *(const half4v*)(O1b + (size_t)r * DDIM + d4);
    const float w0 = wr[r][0], w1 = wr[r][1], rl = wr[r][2];
    float4 res;
    res.x = (o0.x * w0 + (float)o1.x * w1) * rl;
    res.y = (o0.y * w0 + (float)o1.y * w1) * rl;
    res.z = (o0.z * w0 + (float)o1.z * w1) * rl;
    res.w = (o0.w * w0 + (float)o1.w * w1) * rl;
    *(float4*)(Ob + (size_t)r * DDIM + d4) = res;
  }
}

extern "C" void kernel_launch(void* const* d_in, const int* in_sizes, int n_in,
                              void* d_out, int out_size, void* d_ws, size_t ws_size,
                              hipStream_t stream) {
  const float* Qp = (const float*)d_in[0];
  const float* Kp = (const float*)d_in[1];
  const float* Vp = (const float*)d_in[2];
  float* Op = (float*)d_out;

  // ws: Khg fp16 16 MiB | Vtg fp16 16 MiB | O1 fp16 16 MiB | ML fp32 256 KiB
  f16*   Khg = (f16*)d_ws;
  f16*   Vtg = (f16*)((char*)d_ws + (size_t)16777216);
  f16*   O1  = (f16*)((char*)d_ws + (size_t)33554432);
  float* ML  = (float*)((char*)d_ws + (size_t)50331648);

  prep_kernel<<<dim3(2048 + 512), dim3(256), 0, stream>>>(Kp, Vp, Khg, Vtg);
  attn_kernel<<<dim3(256), dim3(512), 0, stream>>>(Qp, Khg, Vtg, Op, O1, ML);
  merge_kernel<<<dim3(256), dim3(256), 0, stream>>>(Op, O1, ML);
}